// Round 2
// baseline (105.902 us; speedup 1.0000x reference)
//
#include <hip/hip_runtime.h>

namespace {
constexpr int NA   = 128;
constexpr int NC2  = NA * (NA - 1) / 2;          // 8128
constexpr int R    = 4;                          // batch rows per block
constexpr int SEGS = 4;                          // pair-space segments per row-group
constexpr int SEG  = NC2 / SEGS;                 // 2032 (8128 = 4*2032 exactly)
constexpr int BT   = 256;                        // threads per block
constexpr float SCALE = 627.5095f * 0.529177f / 100.0f;  // AU2KCALMOLA / MAX_NRF
}

// Triangle packing: pair-slot q in [0, NC2). Chunk u = q>>7 (128 slots)
// covers row a=u+1 (slots r<a -> pair (a,r)) and row b=127-u (slots r>=a ->
// pair (b, r-a)); a+b=128 exactly, so packing is waste-free and index math
// is ~10 int ops. Within a wave, i takes at most 2 values -> LDS broadcast
// (free); j is consecutive per segment -> conflict-free ds_read_b128.
// Output position p = tri(i)+j gives <=2 contiguous store segments per
// wave -> coalesced 256B bursts.
//
// v3 change (single variable vs v2): NON-TEMPORAL stores for out.
// Evidence: v2's occupancy 2x (16->32 waves/CU) was a perfect null
// (82.6->82.4 us), yet kernel ~36 us vs ~15 us on-chip model (LDS 10.2,
// HBM 10.6, VALU 2.8). Theory: the harness's 256 MiB poison-fill runs
// immediately before the kernel inside the timed graph, leaving L3
// 100%-dirty; every store-miss allocation must synchronously evict a
// dirty victim to HBM -> store pipeline serializes on victim writebacks
// (bytes are not the cost; allocate-with-dirty-victim latency is).
// NT stores bypass L2/L3 allocation -> no victim evictions on the
// critical path; output is write-once so caching it buys nothing.
// Prediction: dur 82.4 -> ~61-65 us if theory right; 84-90 if the floor
// is HBM drain contention (informative regression, revert next round).
__global__ __launch_bounds__(BT, 8) void nrf_kernel(
    const float* __restrict__ coords,
    const float* __restrict__ atoms,
    float* __restrict__ out)
{
    __shared__ float4 c4[R][NA];
    const int bid = blockIdx.x;
    const int b0  = (bid >> 2) * R;          // batch row group
    const int q0  = (bid & 3) * SEG;         // pair-space segment [q0, qe)
    const int qe  = q0 + SEG;
    const int tid = threadIdx.x;

    // Stage R rows (R*NA*3 contiguous floats) -> AoS float4 (x,y,z,pad).
    const float* cb = coords + (size_t)b0 * (NA * 3);
    float* c4f = reinterpret_cast<float*>(&c4[0][0]);
    for (int k = tid; k < R * NA * 3; k += BT) {
        int atom = k / 3;                 // constant div -> magic mul
        int comp = k - atom * 3;
        c4f[atom * 4 + comp] = cb[k];     // c4 is row-major, matches flat atom
    }
    __syncthreads();

    float* outb = out + (size_t)b0 * NC2;

    // 2032/256 -> 8 iterations per thread (last one 16/64 lanes masked).
    for (int q = q0 + tid; q < qe; q += BT) {
        int u = q >> 7;
        int r = q & 127;
        int a = u + 1;
        bool lo = (r < a);
        int i = lo ? a : 127 - u;
        int j = lo ? r : r - a;
        int p = ((i * (i - 1)) >> 1) + j;

        float av = atoms[p] * SCALE;      // once per R rows

        float* o = outb + p;
        #pragma unroll
        for (int m = 0; m < R; ++m) {
            float4 ci = c4[m][i];         // <=2 distinct values/wave -> bcast
            float4 cj = c4[m][j];         // lane-consecutive -> conflict-free
            float dx = ci.x - cj.x;
            float dy = ci.y - cj.y;
            float dz = ci.z - cj.z;
            float d2 = dx * dx + dy * dy + dz * dz;
            // ref: 1/(sqrt(d2))^2 == 1/d2 within ~2 ulp; v_rcp_f32 is 1 ulp
            __builtin_nontemporal_store(av * __builtin_amdgcn_rcpf(d2),
                                        o + (size_t)m * NC2);
        }
    }
}

extern "C" void kernel_launch(void* const* d_in, const int* in_sizes, int n_in,
                              void* d_out, int out_size, void* d_ws, size_t ws_size,
                              hipStream_t stream)
{
    const float* coords = (const float*)d_in[0];
    const float* atoms  = (const float*)d_in[1];
    float*       out    = (float*)d_out;
    const int batch = in_sizes[0] / (NA * 3);    // 2048
    nrf_kernel<<<(batch / R) * SEGS, BT, 0, stream>>>(coords, atoms, out);
}

// Round 4
// 88.006 us; speedup vs baseline: 1.2034x; 1.2034x over previous
//
#include <hip/hip_runtime.h>

namespace {
constexpr int NA   = 128;
constexpr int NC2  = NA * (NA - 1) / 2;          // 8128
constexpr int R    = 4;                          // batch rows per block
constexpr int SEGS = 4;                          // group-space segments per row-group
constexpr int BT   = 256;                        // threads per block
// Group space: a "group" = 4 consecutive j within one row i (one float4 of
// output). Full groups only: row i has floor(i/4) of them -> 1984 total.
// Chunk pairing: chunk c (32 slots) covers row iA=c+1 (fA=iA/4 groups) and
// row iB=126-c (fB=iB/4 groups); fA+fB = 31 or 32, so <=1 idle slot per
// chunk (~3% predicated waste, zero divergent splits). Chunk 63 = row 127.
// The 192 leftover elements (j >= 4*floor(i/4), rows with i%4!=0) are swept
// by a tiny scalar epilogue (48 threads per block).
constexpr int SLOTS         = 64 * 32;           // 2048 group slots
constexpr int SLOTS_PER_SEG = SLOTS / SEGS;      // 512 = 2 iters x 256 thr
constexpr int NTAIL         = 192;
constexpr int TAIL_PER_SEG  = NTAIL / SEGS;      // 48
constexpr float SCALE = 627.5095f * 0.529177f / 100.0f;  // AU2KCALMOLA/MAX_NRF

// 4-float vector with 4B alignment: p0 = tri(i)+4t is dword- but not
// 16B-aligned; gfx950 global unaligned vector access handles align(4).
typedef float f4u __attribute__((ext_vector_type(4), aligned(4)));
}

// v4 (resubmit after round-3 GPUAcquisitionTimeout — never ran).
// 4-wide everything. v3's NT experiment surfaced the kernel counters:
// VALUBusy 15%, hbm 2.2 TB/s, conflicts ~0 -> no pipe saturated; the cost
// is per-output instruction issue across LDS/VALU/VMEM with poor overlap
// (NT itself regressed via 1.32x WRITE_SIZE partial-line RMW -> reverted).
// Per 16 outputs (4 j x 4 batch rows) v2 paid: 32 ds_read_b128, 16 store
// _dword, 4 load_dword, 4x index math. v4 pays: 20 ds_read_b128, 4
// store_dwordx4, 1 load_dwordx4, 1x index math. Predicted kernel 44 ->
// 18-24 us; total -> 62-70 us; WRITE_SIZE back to ~67 MB.
__global__ __launch_bounds__(BT, 4) void nrf_kernel(
    const float* __restrict__ coords,
    const float* __restrict__ atoms,
    float* __restrict__ out)
{
    __shared__ float4 c4[R][NA];
    const int bid = blockIdx.x;
    const int b0  = (bid >> 2) * R;          // batch row group
    const int seg = bid & 3;                 // group-space segment
    const int tid = threadIdx.x;

    // Stage R rows (R*NA*3 contiguous floats) -> AoS float4 (x,y,z,pad).
    const float* cb = coords + (size_t)b0 * (NA * 3);
    float* c4f = reinterpret_cast<float*>(&c4[0][0]);
    for (int k = tid; k < R * NA * 3; k += BT) {
        int atom = k / 3;                 // constant div -> magic mul
        int comp = k - atom * 3;
        c4f[atom * 4 + comp] = cb[k];
    }
    __syncthreads();

    float* outb = out + (size_t)b0 * NC2;

    #pragma unroll
    for (int it = 0; it < 2; ++it) {
        const int slot = seg * SLOTS_PER_SEG + it * BT + tid;
        const int c  = slot >> 5;                      // chunk 0..63
        const int s  = slot & 31;                      // slot in chunk
        const int iA = (c < 63) ? c + 1 : 127;
        const int fA = iA >> 2;
        const int fB = (c < 63) ? ((126 - c) >> 2) : 0;
        if (s < fA + fB) {                             // predication, no branch
            const bool lo = s < fA;
            const int i  = lo ? iA : 126 - c;
            const int t  = lo ? s : s - fA;
            const int j0 = t << 2;
            const int p0 = ((i * (i - 1)) >> 1) + j0;  // tri(i)+j0

            f4u av = *reinterpret_cast<const f4u*>(atoms + p0);
            av *= SCALE;                               // once per 16 outputs

            #pragma unroll
            for (int m = 0; m < R; ++m) {
                const float4 ci = c4[m][i];            // 1 b128, wave-broadcast
                f4u res;
                #pragma unroll
                for (int tt = 0; tt < 4; ++tt) {
                    const float4 cj = c4[m][j0 + tt];  // lane-sequential b128
                    const float dx = ci.x - cj.x;
                    const float dy = ci.y - cj.y;
                    const float dz = ci.z - cj.z;
                    const float d2 = dx*dx + dy*dy + dz*dz;
                    // ref: 1/(sqrt d2)^2 == 1/d2 within ~2 ulp
                    res[tt] = av[tt] * __builtin_amdgcn_rcpf(d2);
                }
                *reinterpret_cast<f4u*>(outb + (size_t)m * NC2 + p0) = res;
            }
        }
    }

    // Tail: 192 elements with j >= 4*floor(i/4). Closed form: e = 6*mq + s6,
    // s6 -> (di,dj) in {(1,0),(2,0),(2,1),(3,0),(3,1),(3,2)}; i = 4mq+di,
    // j = 4mq+dj. 48 per segment block; <1 wave-iteration of scalar work.
    if (tid < TAIL_PER_SEG) {
        const int e  = seg * TAIL_PER_SEG + tid;
        const int mq = e / 6;                          // magic mul
        const int s6 = e - 6 * mq;
        const int di = 1 + (s6 >= 1) + (s6 >= 3);
        const int dj = s6 - ((di * (di - 1)) >> 1);
        const int i  = 4 * mq + di;
        const int j  = 4 * mq + dj;
        const int p  = ((i * (i - 1)) >> 1) + j;
        const float av = atoms[p] * SCALE;
        #pragma unroll
        for (int m = 0; m < R; ++m) {
            const float4 ci = c4[m][i];
            const float4 cj = c4[m][j];
            const float dx = ci.x - cj.x;
            const float dy = ci.y - cj.y;
            const float dz = ci.z - cj.z;
            const float d2 = dx*dx + dy*dy + dz*dz;
            outb[(size_t)m * NC2 + p] = av * __builtin_amdgcn_rcpf(d2);
        }
    }
}

extern "C" void kernel_launch(void* const* d_in, const int* in_sizes, int n_in,
                              void* d_out, int out_size, void* d_ws, size_t ws_size,
                              hipStream_t stream)
{
    const float* coords = (const float*)d_in[0];
    const float* atoms  = (const float*)d_in[1];
    float*       out    = (float*)d_out;
    const int batch = in_sizes[0] / (NA * 3);    // 2048
    nrf_kernel<<<(batch / R) * SEGS, BT, 0, stream>>>(coords, atoms, out);
}

// Round 8
// 81.627 us; speedup vs baseline: 1.2974x; 1.0781x over previous
//
#include <hip/hip_runtime.h>

namespace {
constexpr int NA    = 128;
constexpr int NC2   = NA * (NA - 1) / 2;         // 8128
constexpr int BT    = 256;                       // threads per block
constexpr int NSLOT = 64 * 32;                   // 2048 group slots (4-wide j groups)
constexpr int NTAIL = 192;                       // ragged elements (j >= 4*floor(i/4))
constexpr float SCALE = 627.5095f * 0.529177f / 100.0f;  // AU2KCALMOLA/MAX_NRF

// obuf swizzle: word w -> w + 4*(w>>5). Kills the 8-way bank conflict of
// stride-16B scalar writes (lane t writes word ~4t: only 8 banks) by
// rotating banks +4 every 32 words; copy-phase float4 reads stay
// contiguous-and-16B-aligned (4k + 4*(k>>3), mod 4 == 0).
__device__ __forceinline__ int swz(int w) { return w + ((w >> 5) << 2); }
constexpr int OBUF_W = NC2 + ((NC2 >> 5) << 2);  // 9144 words = 36576 B

// 4-float vector, 4B-aligned (atoms load at p0 = tri(i)+4t is dword-aligned).
typedef float f4u __attribute__((ext_vector_type(4), aligned(4)));
}

// v5 (fourth submit; rounds 5-7 all hit GPUAcquisitionTimeout — this exact
// source has never executed on hardware).
// Every access pattern made provably ideal:
//  - v4 post-mortem: cj reads c4[m][j0+tt] had per-lane stride 64B -> 8-way
//    LDS bank conflict (~3x, m136) -> +5.5us vs v2. Fix: SoA soa[3][128];
//    cj = 3 lane-contiguous ds_read_b128 (wave reads 1024B contiguous,
//    conflict-free by construction).
//  - Global stores: v4's align(4) f4u stores possibly scalarized, and were
//    misaligned by tri(i)%4 dwords. Fix: stage the row's 8128 outputs in
//    LDS (swizzled obuf), then copy out as 16B-aligned wave-contiguous
//    dwordx4 - byte-identical pattern to the 6.1 TB/s fillBuffer.
//  - R=1 (one block per batch row): SoA makes cj cost R-independent; whole
//    p-range per block is what makes the aligned copy possible.
// Model: LDS ~8.6us, HBM 10.6us, VALU ~3us -> kernel 13-17us.
__global__ __launch_bounds__(BT, 4) void nrf_kernel(
    const float* __restrict__ coords,
    const float* __restrict__ atoms,
    float* __restrict__ out)
{
    __shared__ __align__(16) float4 c4[NA];       // AoS: ci reads + tail
    __shared__ __align__(16) float  soa[3][NA];   // SoA: cj b128 reads
    __shared__ __align__(16) float  obuf[OBUF_W]; // swizzled output staging

    const int b   = blockIdx.x;                   // one batch row per block
    const int tid = threadIdx.x;

    // Stage 1 row (384 floats) into both AoS float4 and SoA x/y/z.
    const float* cb = coords + (size_t)b * (NA * 3);
    float* c4f = reinterpret_cast<float*>(c4);
    float* sof = &soa[0][0];
    for (int k = tid; k < NA * 3; k += BT) {
        const float v = cb[k];
        const int atom = k / 3;                   // magic mul
        const int comp = k - atom * 3;
        c4f[atom * 4 + comp] = v;
        sof[comp * NA + atom] = v;
    }
    __syncthreads();

    // Main: 2048 slots, each = 4 consecutive j within one row i.
    // Chunk c (32 slots): row iA=c+1 (fA=iA/4 groups, slots s<fA) and row
    // iB=126-c (fB groups, slots s>=fA); chunk 63 = row 127. <=1 idle
    // slot/chunk. (Coverage verified: v4 passed with this scheme.)
    #pragma unroll
    for (int it = 0; it < NSLOT / BT; ++it) {     // 8 iterations
        const int slot = it * BT + tid;
        const int c  = slot >> 5;
        const int s  = slot & 31;
        const int iA = (c < 63) ? c + 1 : 127;
        const int fA = iA >> 2;
        const int fB = (c < 63) ? ((126 - c) >> 2) : 0;
        if (s < fA + fB) {
            const bool lo = s < fA;
            const int i  = lo ? iA : 126 - c;
            const int t  = lo ? s : s - fA;
            const int j0 = t << 2;
            const int p0 = ((i * (i - 1)) >> 1) + j0;

            f4u av = *reinterpret_cast<const f4u*>(atoms + p0);
            av *= SCALE;

            const float4 ci = c4[i];              // <=4 distinct/wave: bcast
            // lane-contiguous, conflict-free b128 (j0 = 4t, lanes t consec)
            const float4 xj = *reinterpret_cast<const float4*>(&soa[0][j0]);
            const float4 yj = *reinterpret_cast<const float4*>(&soa[1][j0]);
            const float4 zj = *reinterpret_cast<const float4*>(&soa[2][j0]);

            const float xr[4] = {xj.x, xj.y, xj.z, xj.w};
            const float yr[4] = {yj.x, yj.y, yj.z, yj.w};
            const float zr[4] = {zj.x, zj.y, zj.z, zj.w};
            #pragma unroll
            for (int tt = 0; tt < 4; ++tt) {
                const float dx = ci.x - xr[tt];
                const float dy = ci.y - yr[tt];
                const float dz = ci.z - zr[tt];
                const float d2 = dx * dx + dy * dy + dz * dz;
                // ref: 1/(sqrt d2)^2 == 1/d2 within ~2 ulp; rcp is 1 ulp
                obuf[swz(p0 + tt)] = av[tt] * __builtin_amdgcn_rcpf(d2);
            }
        }
    }

    // Tail: 192 elements with j >= 4*floor(i/4). e = 6*mq+s6 ->
    // (di,dj) in {(1,0),(2,0),(2,1),(3,0),(3,1),(3,2)}; i=4mq+di, j=4mq+dj.
    if (tid < NTAIL) {
        const int e  = tid;
        const int mq = e / 6;                     // magic mul
        const int s6 = e - 6 * mq;
        const int di = 1 + (s6 >= 1) + (s6 >= 3);
        const int dj = s6 - ((di * (di - 1)) >> 1);
        const int i  = 4 * mq + di;
        const int j  = 4 * mq + dj;
        const int p  = ((i * (i - 1)) >> 1) + j;
        const float4 ci = c4[i];
        const float4 cj = c4[j];
        const float dx = ci.x - cj.x;
        const float dy = ci.y - cj.y;
        const float dz = ci.z - cj.z;
        const float d2 = dx * dx + dy * dy + dz * dz;
        obuf[swz(p)] = atoms[p] * SCALE * __builtin_amdgcn_rcpf(d2);
    }
    __syncthreads();

    // Copy: 2032 float4s, 16B-aligned both sides, wave-contiguous 1KB
    // bursts — the fillBuffer pattern (proven 6.1 TB/s on this chip).
    float* outb = out + (size_t)b * NC2;          // b*32512B: 16B-aligned
    for (int k = tid; k < NC2 / 4; k += BT) {     // 2032 -> 8 iters
        const int ws = swz(4 * k);                // == 4k + 4*(k>>3), %4==0
        *reinterpret_cast<float4*>(outb + 4 * k) =
            *reinterpret_cast<const float4*>(&obuf[ws]);
    }
}

extern "C" void kernel_launch(void* const* d_in, const int* in_sizes, int n_in,
                              void* d_out, int out_size, void* d_ws, size_t ws_size,
                              hipStream_t stream)
{
    const float* coords = (const float*)d_in[0];
    const float* atoms  = (const float*)d_in[1];
    float*       out    = (float*)d_out;
    const int batch = in_sizes[0] / (NA * 3);     // 2048
    nrf_kernel<<<batch, BT, 0, stream>>>(coords, atoms, out);
}